// Round 11
// baseline (662.192 us; speedup 1.0000x reference)
//
#include <hip/hip_runtime.h>
#include <hip/hip_bf16.h>
#include <stdint.h>

#define N_ROWS 8192
#define DIM    1024
#define INV_T  14.2857142857142857f   // 1/0.07

#define BM  256
#define BKB 128                  // K-bytes per LDS tile (fp8: 128 k-elements)
#define NTILE  (N_ROWS / BM)     // 32
#define NSLICE (4 * NTILE)       // 128 col-slices of 64
#define NKT    (DIM / BKB)       // 8 K-tiles
#define NPAIR  528               // 32 diag + 32*31/2 off-diag = 8 * 66
#define PER_XCD (NPAIR / 8)      // 66

typedef int   i32x4 __attribute__((ext_vector_type(4)));
typedef int   i32x8 __attribute__((ext_vector_type(8)));
typedef float f32x4 __attribute__((ext_vector_type(4)));

// ---------------- kernel 1: row-normalize f32 -> fp8 e4m3 (OCP) ----------------
__global__ __launch_bounds__(256) void norm_kernel(
    const float* __restrict__ V, unsigned char* __restrict__ A8)
{
    const int row  = blockIdx.x;
    const int tid  = threadIdx.x;
    const int lane = tid & 63, wid = tid >> 6;

    const float4* vp = (const float4*)(V + (size_t)row * DIM);
    float4 v = vp[tid];
    float ss = v.x*v.x + v.y*v.y + v.z*v.z + v.w*v.w;
    #pragma unroll
    for (int off = 32; off > 0; off >>= 1) ss += __shfl_down(ss, off, 64);

    __shared__ float wsum[4];
    if (lane == 0) wsum[wid] = ss;
    __syncthreads();
    const float inv = 1.0f / sqrtf(wsum[0] + wsum[1] + wsum[2] + wsum[3]);

    int pk = __builtin_amdgcn_cvt_pk_fp8_f32(v.x * inv, v.y * inv, 0,  false);
    pk     = __builtin_amdgcn_cvt_pk_fp8_f32(v.z * inv, v.w * inv, pk, true);
    ((int*)(A8 + (size_t)row * DIM))[tid] = pk;
}

// ---------------- kernel 2: 256^2 8-wave phase-interleaved sim GEMM ----------------
// Identical to R9/R10 except __launch_bounds__(512, 1). Empirics across
// R3/R8/R9: hipcc's 2nd arg behaves as min BLOCKS per CU here -- (512,2) and
// the bare default both produced a 128-VGPR cap (4 waves/EU) and spilled the
// 128-VGPR accumulator (FETCH 845MB, MfmaUtil 2.2%). (512,1) -> 1 block/CU ->
// 2 waves/EU -> 256-VGPR band. acc(128) + frags(48) + addr(~40) fits.
__global__ __launch_bounds__(512, 1) void sim_kernel(
    const unsigned char* __restrict__ A8, const int* __restrict__ labels,
    float* __restrict__ psum, float* __restrict__ ppos, float* __restrict__ pcnt)
{
    __shared__ __align__(16) unsigned char As[2][BM * BKB];  // 2 x 32 KB
    __shared__ __align__(16) unsigned char Bs[2][BM * BKB];  // 2 x 32 KB
    __shared__ int labR[BM], labC[BM];                       // 2 KB

    // ---- supertile pair decode (uniform scalar) ----
    const int b = blockIdx.x;                    // 0..527
    const int v = (b & 7) * PER_XCD + (b >> 3);  // XCD-contiguous index
    int rem = v, RTs = 0, rowsz = 36 + 3 * 64;   // 228,164,100,36
    while (rem >= rowsz) { rem -= rowsz; ++RTs; rowsz -= 64; }
    int rt, ct;
    if (rem < 36) {                              // diagonal supertile
        int i = 0, left = 8;
        while (rem >= left) { rem -= left; ++i; --left; }
        rt = RTs * 8 + i;  ct = RTs * 8 + i + rem;
    } else {                                     // off-diagonal supertile
        const int o   = rem - 36;
        const int CTs = RTs + 1 + (o >> 6);
        const int w   = o & 63;
        rt = RTs * 8 + (w >> 3);
        ct = CTs * 8 + (w & 7);
    }
    const bool isDiag = (rt == ct);

    const int tid  = threadIdx.x;
    const int lane = tid & 63;
    const int wid  = tid >> 6;      // 0..7
    const int wr   = wid >> 2;      // 0..1 (row half)
    const int wc   = wid & 3;       // 0..3 (col quarter)
    const int t    = lane >> 4;     // k-group 0..3

    const int rbase = rt * BM;
    const int cbase = ct * BM;

    // label cache
    if (tid < BM) {
        labR[tid] = labels[rbase + tid];
        labC[tid] = labels[cbase + tid];
    }

    f32x4 acc[8][4];
    #pragma unroll
    for (int m = 0; m < 8; ++m)
        #pragma unroll
        for (int n = 0; n < 4; ++n)
            acc[m][n] = (f32x4){0.f, 0.f, 0.f, 0.f};

    // staging: linear LDS dest, source 16B-chunk XOR-swizzled (^row&7);
    // reads apply the same XOR (rule-21 involution pair). 4 gloads per call.
    #define STAGE_T(buf, kt, SRC, DST)                                             \
    {                                                                              \
        const int kbase = (kt) * BKB;                                              \
        _Pragma("unroll")                                                          \
        for (int i = 0; i < 4; ++i) {                                              \
            const int c    = i * 512 + tid;                                        \
            const int rowc = c >> 3;                                               \
            const int kcs  = (c & 7) ^ (rowc & 7);                                 \
            const unsigned char* g = A8 + (size_t)((SRC) + rowc) * DIM + kbase + kcs * 16; \
            __builtin_amdgcn_global_load_lds(                                      \
                (const __attribute__((address_space(1))) void*)g,                  \
                (__attribute__((address_space(3))) void*)(DST[buf] + i * 8192 + wid * 1024), \
                16, 0, 0);                                                         \
        }                                                                          \
    }
    #define STAGE_A(buf, kt) STAGE_T(buf, kt, rbase, As)
    #define STAGE_B(buf, kt) STAGE_T(buf, kt, cbase, Bs)

    // fragment reads (ds_read_b128 pairs per fragment)
    #define READ_A(dst, mh)                                                        \
        _Pragma("unroll")                                                          \
        for (int m = 0; m < 4; ++m) {                                              \
            const int rowa = wr * 128 + ((mh) * 4 + m) * 16 + (lane & 15);         \
            const int c0 = ((2 * t)     ^ (rowa & 7)) << 4;                        \
            const int c1 = ((2 * t + 1) ^ (rowa & 7)) << 4;                        \
            i32x4 lo = *(const i32x4*)(As[cur] + rowa * BKB + c0);                 \
            i32x4 hi = *(const i32x4*)(As[cur] + rowa * BKB + c1);                 \
            i32x8 f; f[0]=lo[0]; f[1]=lo[1]; f[2]=lo[2]; f[3]=lo[3];               \
                     f[4]=hi[0]; f[5]=hi[1]; f[6]=hi[2]; f[7]=hi[3];               \
            dst[m] = f;                                                            \
        }
    #define READ_B(dst, nh)                                                        \
        _Pragma("unroll")                                                          \
        for (int n = 0; n < 2; ++n) {                                              \
            const int rowb = wc * 64 + ((nh) * 2 + n) * 16 + (lane & 15);          \
            const int c0 = ((2 * t)     ^ (rowb & 7)) << 4;                        \
            const int c1 = ((2 * t + 1) ^ (rowb & 7)) << 4;                        \
            i32x4 lo = *(const i32x4*)(Bs[cur] + rowb * BKB + c0);                 \
            i32x4 hi = *(const i32x4*)(Bs[cur] + rowb * BKB + c1);                 \
            i32x8 f; f[0]=lo[0]; f[1]=lo[1]; f[2]=lo[2]; f[3]=lo[3];               \
                     f[4]=hi[0]; f[5]=hi[1]; f[6]=hi[2]; f[7]=hi[3];               \
            dst[n] = f;                                                            \
        }

    // one phase: bar -> lgkm0 (+sched fence, rule 18) -> prio -> 8 MFMA -> prio -> bar
    #define DO_PHASE(afr, bfr, mh, nh)                                             \
    {                                                                              \
        __builtin_amdgcn_s_barrier();                                              \
        asm volatile("s_waitcnt lgkmcnt(0)" ::: "memory");                         \
        __builtin_amdgcn_sched_barrier(0);                                         \
        __builtin_amdgcn_s_setprio(1);                                             \
        _Pragma("unroll")                                                          \
        for (int m = 0; m < 4; ++m)                                                \
            _Pragma("unroll")                                                      \
            for (int n = 0; n < 2; ++n)                                            \
                acc[(mh) * 4 + m][(nh) * 2 + n] =                                  \
                    __builtin_amdgcn_mfma_scale_f32_16x16x128_f8f6f4(              \
                        afr[m], bfr[n], acc[(mh) * 4 + m][(nh) * 2 + n],           \
                        0, 0, 0, 0x7F, 0, 0x7F);                                   \
        __builtin_amdgcn_s_setprio(0);                                             \
        __builtin_amdgcn_s_barrier();                                              \
    }

    // prologue: stage tile 0, drain, publish
    STAGE_A(0, 0);
    STAGE_B(0, 0);
    asm volatile("s_waitcnt vmcnt(0)" ::: "memory");
    __builtin_amdgcn_s_barrier();

    int cur = 0;
    for (int kt = 0; kt < NKT; ++kt) {
        i32x8 a[4], bb[2];
        READ_A(a, 0); READ_B(bb, 0);
        if (kt + 1 < NKT) STAGE_A(cur ^ 1, kt + 1);   // prefetch A of next tile
        DO_PHASE(a, bb, 0, 0);

        READ_A(a, 1);                                 // A-half 1 (B0 reused)
        if (kt + 1 < NKT) STAGE_B(cur ^ 1, kt + 1);   // prefetch B of next tile
        DO_PHASE(a, bb, 1, 0);

        READ_B(bb, 1);                                // B-half 1 (A1 reused)
        DO_PHASE(a, bb, 1, 1);

        READ_A(a, 0);                                 // A-half 0 again (B1 reused)
        DO_PHASE(a, bb, 0, 1);

        if (kt + 1 < NKT) {
            // loads issued >=2 phases (~400+ cyc of MFMA) ago: residual wait only
            asm volatile("s_waitcnt vmcnt(0)" ::: "memory");
            __builtin_amdgcn_s_barrier();
            cur ^= 1;
        }
    }

    // ---------------- epilogue ----------------
    // acc[mp][n][r] -> row = rbase + wr*128 + mp*16 + t*4 + r,
    //                  col = cbase + wc*64 + (lane&15) + n*16
    const int colLoc0 = wc * 64 + (lane & 15);
    int labc[4];
    #pragma unroll
    for (int n = 0; n < 4; ++n) labc[n] = labC[colLoc0 + n * 16];

    float csum[4], cpos[4], ccnt[4];
    #pragma unroll
    for (int n = 0; n < 4; ++n) { csum[n] = 0.f; cpos[n] = 0.f; ccnt[n] = 0.f; }

    #pragma unroll
    for (int mh = 0; mh < 2; ++mh) {
        #pragma unroll
        for (int mq = 0; mq < 4; ++mq) {
            const int mp = mh * 4 + mq;
            const int rowLocBase = wr * 128 + mp * 16 + t * 4;
            float se[4], pp[4], cc[4];
            #pragma unroll
            for (int r = 0; r < 4; ++r) { se[r] = 0.f; pp[r] = 0.f; cc[r] = 0.f; }

            #pragma unroll
            for (int n = 0; n < 4; ++n) {
                #pragma unroll
                for (int r = 0; r < 4; ++r) {
                    const float s    = acc[mp][n][r] * INV_T;
                    const int   labr = labR[rowLocBase + r];
                    bool diag = false;
                    if (isDiag)
                        diag = (rowLocBase + r) == (colLoc0 + n * 16);
                    const float e = diag ? 0.f : __expf(s);
                    se[r] += e;
                    const bool same = (labr == labc[n]) && !diag;
                    if (same) { pp[r] += s; cc[r] += 1.f; }
                    if (!isDiag) {
                        csum[n] += e;
                        if (same) { cpos[n] += s; ccnt[n] += 1.f; }
                    }
                }
            }
            // row-side reduce across the 16 lanes sharing this 64-col slice
            #pragma unroll
            for (int r = 0; r < 4; ++r) {
                float s2 = se[r], p2 = pp[r], c2 = cc[r];
                #pragma unroll
                for (int off = 1; off < 16; off <<= 1) {
                    s2 += __shfl_xor(s2, off, 16);
                    p2 += __shfl_xor(p2, off, 16);
                    c2 += __shfl_xor(c2, off, 16);
                }
                if ((lane & 15) == 0) {
                    const int row = rbase + rowLocBase + r;
                    const size_t idx = (size_t)(ct * 4 + wc) * N_ROWS + row;
                    psum[idx] = s2;
                    ppos[idx] = p2;
                    pcnt[idx] = c2;
                }
            }
        }
        // col-side flush for this 64-row half (off-diag only)
        if (!isDiag) {
            #pragma unroll
            for (int n = 0; n < 4; ++n) {
                float s2 = csum[n], p2 = cpos[n], c2 = ccnt[n];
                s2 += __shfl_xor(s2, 16, 64); s2 += __shfl_xor(s2, 32, 64);
                p2 += __shfl_xor(p2, 16, 64); p2 += __shfl_xor(p2, 32, 64);
                c2 += __shfl_xor(c2, 16, 64); c2 += __shfl_xor(c2, 32, 64);
                if (lane < 16) {
                    const int gcol = cbase + wc * 64 + lane + n * 16;
                    const size_t idx = (size_t)(rt * 4 + wr * 2 + mh) * N_ROWS + gcol;
                    psum[idx] = s2;
                    ppos[idx] = p2;
                    pcnt[idx] = c2;
                }
                csum[n] = 0.f; cpos[n] = 0.f; ccnt[n] = 0.f;
            }
        }
    }
}

// ---------------- kernel 3: fused finalize (per-row logsumexp + global sum) ----
__global__ __launch_bounds__(256) void finalize_kernel(
    const float* __restrict__ psum, const float* __restrict__ ppos,
    const float* __restrict__ pcnt, float* __restrict__ out)
{
    const int row  = blockIdx.x * 256 + threadIdx.x;
    const int lane = threadIdx.x & 63, wid = threadIdx.x >> 6;

    float s = 0.f, p = 0.f, c = 0.f;
    #pragma unroll 8
    for (int sl = 0; sl < NSLICE; ++sl) {
        const size_t idx = (size_t)sl * N_ROWS + row;
        s += psum[idx];
        p += ppos[idx];
        c += pcnt[idx];
    }
    float per = (c > 0.f) ? (logf(s) - p / c) : 0.f;
    #pragma unroll
    for (int off = 32; off > 0; off >>= 1) per += __shfl_down(per, off, 64);
    __shared__ float w4[4];
    if (lane == 0) w4[wid] = per;
    __syncthreads();
    if (threadIdx.x == 0)
        atomicAdd(out, w4[0] + w4[1] + w4[2] + w4[3]);
}

extern "C" void kernel_launch(void* const* d_in, const int* in_sizes, int n_in,
                              void* d_out, int out_size, void* d_ws, size_t ws_size,
                              hipStream_t stream) {
    const float* V      = (const float*)d_in[0];
    const int*   labels = (const int*)d_in[1];
    float*       out    = (float*)d_out;

    // ws layout: A8 8 MB | psum 4 MB | ppos 4 MB | pcnt 4 MB
    unsigned char* A8 = (unsigned char*)d_ws;
    char* base = (char*)d_ws + (size_t)N_ROWS * DIM;
    float* psum = (float*)(base);
    float* ppos = (float*)(base + (size_t)NSLICE * N_ROWS * 4);
    float* pcnt = (float*)(base + (size_t)NSLICE * N_ROWS * 8);

    hipMemsetAsync(out, 0, sizeof(float), stream);
    norm_kernel<<<N_ROWS, 256, 0, stream>>>(V, A8);
    sim_kernel<<<NPAIR, 512, 0, stream>>>(A8, labels, psum, ppos, pcnt);
    finalize_kernel<<<N_ROWS / 256, 256, 0, stream>>>(psum, ppos, pcnt, out);
}

// Round 12
// 90.145 us; speedup vs baseline: 7.3459x; 7.3459x over previous
//
#include <hip/hip_runtime.h>
#include <hip/hip_bf16.h>
#include <stdint.h>

#define N_ROWS 8192
#define DIM    1024
#define INV_T  14.2857142857142857f   // 1/0.07

#define BM  128
#define BKB 128                  // K-bytes per LDS tile (fp8: 128 k-elements)
#define NTILE  (N_ROWS / BM)     // 64
#define NSLICE (2 * NTILE)       // 128 col-slices of 64
#define NKT    (DIM / BKB)       // 8 K-tiles
#define NPAIR  2080              // 64 diag + 64*63/2 off-diag
#define PER_XCD (NPAIR / 8)      // 260

typedef int   i32x4 __attribute__((ext_vector_type(4)));
typedef int   i32x8 __attribute__((ext_vector_type(8)));
typedef float f32x4 __attribute__((ext_vector_type(4)));

// ---------------- kernel 1: row-normalize f32 -> fp8 e4m3 (OCP) ----------------
__global__ __launch_bounds__(256) void norm_kernel(
    const float* __restrict__ V, unsigned char* __restrict__ A8)
{
    const int row  = blockIdx.x;
    const int tid  = threadIdx.x;
    const int lane = tid & 63, wid = tid >> 6;

    const float4* vp = (const float4*)(V + (size_t)row * DIM);
    float4 v = vp[tid];
    float ss = v.x*v.x + v.y*v.y + v.z*v.z + v.w*v.w;
    #pragma unroll
    for (int off = 32; off > 0; off >>= 1) ss += __shfl_down(ss, off, 64);

    __shared__ float wsum[4];
    if (lane == 0) wsum[wid] = ss;
    __syncthreads();
    const float inv = 1.0f / sqrtf(wsum[0] + wsum[1] + wsum[2] + wsum[3]);

    int pk = __builtin_amdgcn_cvt_pk_fp8_f32(v.x * inv, v.y * inv, 0,  false);
    pk     = __builtin_amdgcn_cvt_pk_fp8_f32(v.z * inv, v.w * inv, pk, true);
    ((int*)(A8 + (size_t)row * DIM))[tid] = pk;
}

// ---------------- kernel 2: fused symmetric sim GEMM (MX-fp8) + epilogue ----------------
// R7 structure (proven 66us): 2080 pair-blocks, supertile-banded XCD-contiguous
// mapping (FETCH 38MB), single 32KB LDS buffer, 2-phase reordered loop
// (reads -> bar -> STAGE(kt+1) -> MFMA -> bar), transposed partials.
// R12 delta: i32x8 fragment concat via __builtin_shufflevector (kills the
// per-fragment element-copy v_movs that inflated VALUBusy to 33%).
__global__ __launch_bounds__(256, 3) void sim_kernel(
    const unsigned char* __restrict__ A8, const int* __restrict__ labels,
    float* __restrict__ psum, float* __restrict__ ppos, float* __restrict__ pcnt)
{
    __shared__ __align__(16) unsigned char As[BM * BKB];   // 16 KB
    __shared__ __align__(16) unsigned char Bs[BM * BKB];   // 16 KB

    // ---- supertile pair decode (uniform per block, scalar) ----
    const int b = blockIdx.x;                    // 0..2079
    const int v = (b & 7) * PER_XCD + (b >> 3);  // XCD-contiguous virtual index
    int rem = v, RT = 0, rowsz = 36 + 7 * 64;    // ST-row RT size
    while (rem >= rowsz) { rem -= rowsz; ++RT; rowsz -= 64; }
    int rt, ct;
    if (rem < 36) {                              // diagonal supertile
        int i = 0, left = 8;
        while (rem >= left) { rem -= left; ++i; --left; }
        rt = RT * 8 + i;  ct = RT * 8 + i + rem;
    } else {                                     // off-diagonal supertile
        const int o  = rem - 36;
        const int CT = RT + 1 + (o >> 6);
        const int w  = o & 63;
        rt = RT * 8 + (w >> 3);
        ct = CT * 8 + (w & 7);
    }
    const bool isDiag = (rt == ct);

    const int tid  = threadIdx.x;
    const int lane = tid & 63;
    const int wid  = tid >> 6;
    const int wr   = wid >> 1;      // wave row 0..1
    const int wc   = wid & 1;       // wave col 0..1

    const int rbase = rt * BM;
    const int cbase = ct * BM;

    const int rowq = rbase + wr * 64 + ((lane >> 4) << 2);
    const int col0 = cbase + wc * 64 + (lane & 15);

    int labr[16];
    #pragma unroll
    for (int m = 0; m < 4; ++m)
        #pragma unroll
        for (int r = 0; r < 4; ++r)
            labr[m * 4 + r] = labels[rowq + m * 16 + r];
    int labc[4];
    #pragma unroll
    for (int n = 0; n < 4; ++n) labc[n] = labels[col0 + n * 16];

    f32x4 acc[4][4];
    #pragma unroll
    for (int m = 0; m < 4; ++m)
        #pragma unroll
        for (int n = 0; n < 4; ++n)
            acc[m][n] = (f32x4){0.f, 0.f, 0.f, 0.f};

    // staging: linear LDS dest; source 16B-chunk XOR-swizzled (^row&7), read
    // side applies the same XOR (rule 21 involution pair).
    #define STAGE(kt)                                                              \
    {                                                                              \
        const int kbase = (kt) * BKB;                                              \
        _Pragma("unroll")                                                          \
        for (int i = 0; i < 4; ++i) {                                              \
            const int c    = i * 256 + tid;                                        \
            const int rowc = c >> 3;                                               \
            const int kcs  = (c & 7) ^ (rowc & 7);                                 \
            const unsigned char* gA = A8 + (size_t)(rbase + rowc) * DIM + kbase + kcs * 16; \
            const unsigned char* gB = A8 + (size_t)(cbase + rowc) * DIM + kbase + kcs * 16; \
            const int ldsOff = i * 4096 + wid * 1024;   /* +lane*16 by HW */       \
            __builtin_amdgcn_global_load_lds(                                      \
                (const __attribute__((address_space(1))) void*)gA,                 \
                (__attribute__((address_space(3))) void*)(As + ldsOff),            \
                16, 0, 0);                                                         \
            __builtin_amdgcn_global_load_lds(                                      \
                (const __attribute__((address_space(1))) void*)gB,                 \
                (__attribute__((address_space(3))) void*)(Bs + ldsOff),            \
                16, 0, 0);                                                         \
        }                                                                          \
    }

    const int t = lane >> 4;        // K-block 0..3 (32 k-bytes each)

    STAGE(0);
    __syncthreads();                // tile 0 resident

    for (int kt = 0; kt < NKT; ++kt) {
        // ---- phase A: pull all fragments of tile kt into registers
        i32x8 a8[4], b8[4];
        #pragma unroll
        for (int m = 0; m < 4; ++m) {
            const int rowa = wr * 64 + m * 16 + (lane & 15);
            const int c0 = ((2 * t)     ^ (rowa & 7)) << 4;
            const int c1 = ((2 * t + 1) ^ (rowa & 7)) << 4;
            i32x4 lo = *(const i32x4*)(As + rowa * BKB + c0);
            i32x4 hi = *(const i32x4*)(As + rowa * BKB + c1);
            a8[m] = __builtin_shufflevector(lo, hi, 0, 1, 2, 3, 4, 5, 6, 7);
        }
        #pragma unroll
        for (int n = 0; n < 4; ++n) {
            const int rowb = wc * 64 + n * 16 + (lane & 15);
            const int c0 = ((2 * t)     ^ (rowb & 7)) << 4;
            const int c1 = ((2 * t + 1) ^ (rowb & 7)) << 4;
            i32x4 lo = *(const i32x4*)(Bs + rowb * BKB + c0);
            i32x4 hi = *(const i32x4*)(Bs + rowb * BKB + c1);
            b8[n] = __builtin_shufflevector(lo, hi, 0, 1, 2, 3, 4, 5, 6, 7);
        }
        __syncthreads();            // lgkm(0): all waves' LDS reads complete
                                    // (vmcnt already 0 from previous iteration)

        // ---- phase B: refill LDS for kt+1 while MFMAs run from registers
        if (kt + 1 < NKT) STAGE(kt + 1);

        __builtin_amdgcn_s_setprio(1);
        #pragma unroll
        for (int m = 0; m < 4; ++m)
            #pragma unroll
            for (int n = 0; n < 4; ++n)
                acc[m][n] = __builtin_amdgcn_mfma_scale_f32_16x16x128_f8f6f4(
                    a8[m], b8[n], acc[m][n],
                    0 /*A fmt fp8*/, 0 /*B fmt fp8*/,
                    0, 0x7F /*scaleA = 2^0*/, 0, 0x7F /*scaleB = 2^0*/);
        __builtin_amdgcn_s_setprio(0);

        __syncthreads();            // drains vmcnt(0): tile kt+1 resident
    }

    // ---------------- epilogue ----------------
    float sum_p[16], pos_p[16], cnt_p[16];
    #pragma unroll
    for (int i = 0; i < 16; ++i) { sum_p[i] = 0.f; pos_p[i] = 0.f; cnt_p[i] = 0.f; }
    float csum[4], cpos[4], ccnt[4];
    #pragma unroll
    for (int n = 0; n < 4; ++n) { csum[n] = 0.f; cpos[n] = 0.f; ccnt[n] = 0.f; }

    if (isDiag) {
        #pragma unroll
        for (int m = 0; m < 4; ++m)
            #pragma unroll
            for (int n = 0; n < 4; ++n) {
                const int gcol = col0 + n * 16;
                #pragma unroll
                for (int r = 0; r < 4; ++r) {
                    const float s    = acc[m][n][r] * INV_T;
                    const int   i16  = m * 4 + r;
                    const int   grow = rowq + m * 16 + r;
                    const bool  diag = (grow == gcol);
                    sum_p[i16] += diag ? 0.f : __expf(s);
                    if ((labr[i16] == labc[n]) && !diag) {
                        pos_p[i16] += s; cnt_p[i16] += 1.f;
                    }
                }
            }
    } else {
        #pragma unroll
        for (int m = 0; m < 4; ++m)
            #pragma unroll
            for (int n = 0; n < 4; ++n) {
                #pragma unroll
                for (int r = 0; r < 4; ++r) {
                    const float s   = acc[m][n][r] * INV_T;
                    const int   i16 = m * 4 + r;
                    const float e   = __expf(s);
                    sum_p[i16] += e;
                    csum[n]    += e;
                    if (labr[i16] == labc[n]) {
                        pos_p[i16] += s; cnt_p[i16] += 1.f;
                        cpos[n]    += s; ccnt[n]    += 1.f;
                    }
                }
            }
    }

    // row-side: reduce across 16 lanes sharing each row -> partial[ct*2+wc][row]
    #pragma unroll
    for (int i = 0; i < 16; ++i) {
        float se = sum_p[i], pp = pos_p[i], cc = cnt_p[i];
        #pragma unroll
        for (int off = 1; off < 16; off <<= 1) {
            se += __shfl_xor(se, off, 16);
            pp += __shfl_xor(pp, off, 16);
            cc += __shfl_xor(cc, off, 16);
        }
        if ((lane & 15) == 0) {
            const int row = rowq + (i >> 2) * 16 + (i & 3);
            const size_t idx = (size_t)(ct * 2 + wc) * N_ROWS + row;
            psum[idx] = se;
            ppos[idx] = pp;
            pcnt[idx] = cc;
        }
    }

    // col-side (off-diag only): reduce across 4 lane-groups -> partial[rt*2+wr][col]
    if (!isDiag) {
        #pragma unroll
        for (int n = 0; n < 4; ++n) {
            float se = csum[n], pp = cpos[n], cc = ccnt[n];
            se += __shfl_xor(se, 16, 64); se += __shfl_xor(se, 32, 64);
            pp += __shfl_xor(pp, 16, 64); pp += __shfl_xor(pp, 32, 64);
            cc += __shfl_xor(cc, 16, 64); cc += __shfl_xor(cc, 32, 64);
            if (lane < 16) {
                const int gcol = col0 + n * 16;
                const size_t idx = (size_t)(rt * 2 + wr) * N_ROWS + gcol;
                psum[idx] = se;
                ppos[idx] = pp;
                pcnt[idx] = cc;
            }
        }
    }
}

// ---------------- kernel 3: fused finalize (per-row logsumexp + global sum) ----
__global__ __launch_bounds__(256) void finalize_kernel(
    const float* __restrict__ psum, const float* __restrict__ ppos,
    const float* __restrict__ pcnt, float* __restrict__ out)
{
    const int row  = blockIdx.x * 256 + threadIdx.x;
    const int lane = threadIdx.x & 63, wid = threadIdx.x >> 6;

    float s = 0.f, p = 0.f, c = 0.f;
    #pragma unroll 8
    for (int sl = 0; sl < NSLICE; ++sl) {
        const size_t idx = (size_t)sl * N_ROWS + row;
        s += psum[idx];
        p += ppos[idx];
        c += pcnt[idx];
    }
    float per = (c > 0.f) ? (logf(s) - p / c) : 0.f;
    #pragma unroll
    for (int off = 32; off > 0; off >>= 1) per += __shfl_down(per, off, 64);
    __shared__ float w4[4];
    if (lane == 0) w4[wid] = per;
    __syncthreads();
    if (threadIdx.x == 0)
        atomicAdd(out, w4[0] + w4[1] + w4[2] + w4[3]);
}

extern "C" void kernel_launch(void* const* d_in, const int* in_sizes, int n_in,
                              void* d_out, int out_size, void* d_ws, size_t ws_size,
                              hipStream_t stream) {
    const float* V      = (const float*)d_in[0];
    const int*   labels = (const int*)d_in[1];
    float*       out    = (float*)d_out;

    // ws layout: A8 8 MB | psum 4 MB | ppos 4 MB | pcnt 4 MB
    unsigned char* A8 = (unsigned char*)d_ws;
    char* base = (char*)d_ws + (size_t)N_ROWS * DIM;
    float* psum = (float*)(base);
    float* ppos = (float*)(base + (size_t)NSLICE * N_ROWS * 4);
    float* pcnt = (float*)(base + (size_t)NSLICE * N_ROWS * 8);

    hipMemsetAsync(out, 0, sizeof(float), stream);
    norm_kernel<<<N_ROWS, 256, 0, stream>>>(V, A8);
    sim_kernel<<<NPAIR, 256, 0, stream>>>(A8, labels, psum, ppos, pcnt);
    finalize_kernel<<<N_ROWS / 256, 256, 0, stream>>>(psum, ppos, pcnt, out);
}

// Round 13
// 75.474 us; speedup vs baseline: 8.7738x; 1.1944x over previous
//
#include <hip/hip_runtime.h>
#include <hip/hip_bf16.h>
#include <stdint.h>

#define N_ROWS 8192
#define DIM    1024
#define INV_T  14.2857142857142857f   // 1/0.07
#define SCL    (INV_T / 1024.0f)      // acc holds 1024*sim (values packed as 32*x)

#define BM   128
#define RPB  512                 // row pitch bytes (fp4: DIM/2)
#define TKB  64                  // K-tile bytes per row (128 k-elems * 0.5B)
#define NTILE  (N_ROWS / BM)     // 64
#define NSLICE (2 * NTILE)       // 128 col-slices of 64
#define NKT    8                 // 1024 / 128
#define NPAIR  2080              // 64 diag + 64*63/2 off-diag
#define PER_XCD (NPAIR / 8)      // 260

typedef int   i32x4 __attribute__((ext_vector_type(4)));
typedef int   i32x8 __attribute__((ext_vector_type(8)));
typedef float f32x4 __attribute__((ext_vector_type(4)));

// e2m1 encode of y (round-to-nearest): values 0,.5,1,1.5,2,3,4,6 + sign bit
__device__ __forceinline__ unsigned e2m1(float y) {
    const float a = fabsf(y);
    unsigned c = a < 0.25f ? 0u : a < 0.75f ? 1u : a < 1.25f ? 2u :
                 a < 1.75f ? 3u : a < 2.5f  ? 4u : a < 3.5f  ? 5u :
                 a < 5.0f  ? 6u : 7u;
    return c | (y < 0.f ? 8u : 0u);
}

// ---------------- kernel 1: row-normalize f32 -> fp4 e2m1 (x32 prescale) ----
__global__ __launch_bounds__(256) void norm_kernel(
    const float* __restrict__ V, unsigned char* __restrict__ A4)
{
    const int row  = blockIdx.x;
    const int tid  = threadIdx.x;
    const int lane = tid & 63, wid = tid >> 6;

    const float4* vp = (const float4*)(V + (size_t)row * DIM);
    float4 v = vp[tid];
    float ss = v.x*v.x + v.y*v.y + v.z*v.z + v.w*v.w;
    #pragma unroll
    for (int off = 32; off > 0; off >>= 1) ss += __shfl_down(ss, off, 64);

    __shared__ float wsum[4];
    if (lane == 0) wsum[wid] = ss;
    __syncthreads();
    const float inv = 32.0f / sqrtf(wsum[0] + wsum[1] + wsum[2] + wsum[3]);

    const unsigned e0 = e2m1(v.x * inv), e1 = e2m1(v.y * inv);
    const unsigned e2 = e2m1(v.z * inv), e3 = e2m1(v.w * inv);
    ((unsigned short*)(A4 + (size_t)row * RPB))[tid] =
        (unsigned short)(e0 | (e1 << 4) | (e2 << 8) | (e3 << 12));
}

// ---------------- kernel 2: fused symmetric sim GEMM (MX-fp4) + epilogue ----------------
// R7/R12 shell (proven): 2080 pair-blocks, supertile-banded XCD-contiguous map,
// single LDS buffer (now 2x8KB), 2-phase reordered loop, transposed partials.
// R13 delta: fp4 e2m1 operands -> one ds_read_b128 per fragment (LDS reads
// halved), staging bytes halved, MFMA fmt=4. Scale stays 0x7F (=1.0); the
// 32x32 prescale is divided out in the epilogue (SCL).
__global__ __launch_bounds__(256, 3) void sim_kernel(
    const unsigned char* __restrict__ A4, const int* __restrict__ labels,
    float* __restrict__ psum, float* __restrict__ ppos, float* __restrict__ pcnt)
{
    __shared__ __align__(16) unsigned char As[BM * TKB];   // 8 KB
    __shared__ __align__(16) unsigned char Bs[BM * TKB];   // 8 KB

    // ---- supertile pair decode (uniform per block, scalar) ----
    const int b = blockIdx.x;                    // 0..2079
    const int v = (b & 7) * PER_XCD + (b >> 3);  // XCD-contiguous virtual index
    int rem = v, RT = 0, rowsz = 36 + 7 * 64;    // ST-row RT size
    while (rem >= rowsz) { rem -= rowsz; ++RT; rowsz -= 64; }
    int rt, ct;
    if (rem < 36) {                              // diagonal supertile
        int i = 0, left = 8;
        while (rem >= left) { rem -= left; ++i; --left; }
        rt = RT * 8 + i;  ct = RT * 8 + i + rem;
    } else {                                     // off-diagonal supertile
        const int o  = rem - 36;
        const int CT = RT + 1 + (o >> 6);
        const int w  = o & 63;
        rt = RT * 8 + (w >> 3);
        ct = CT * 8 + (w & 7);
    }
    const bool isDiag = (rt == ct);

    const int tid  = threadIdx.x;
    const int lane = tid & 63;
    const int wid  = tid >> 6;
    const int wr   = wid >> 1;      // wave row 0..1
    const int wc   = wid & 1;       // wave col 0..1

    const int rbase = rt * BM;
    const int cbase = ct * BM;

    const int rowq = rbase + wr * 64 + ((lane >> 4) << 2);
    const int col0 = cbase + wc * 64 + (lane & 15);

    int labr[16];
    #pragma unroll
    for (int m = 0; m < 4; ++m)
        #pragma unroll
        for (int r = 0; r < 4; ++r)
            labr[m * 4 + r] = labels[rowq + m * 16 + r];
    int labc[4];
    #pragma unroll
    for (int n = 0; n < 4; ++n) labc[n] = labels[col0 + n * 16];

    f32x4 acc[4][4];
    #pragma unroll
    for (int m = 0; m < 4; ++m)
        #pragma unroll
        for (int n = 0; n < 4; ++n)
            acc[m][n] = (f32x4){0.f, 0.f, 0.f, 0.f};

    // staging: linear LDS dest; source 16B-chunk XOR-swizzled (^row&3, 4 chunks
    // per 64B row); read side applies the same XOR (rule-21 involution pair).
    // 2 gloads per matrix per K-tile (8KB / 256thr / 16B = 2 passes).
    #define STAGE(kt)                                                              \
    {                                                                              \
        const int kbase = (kt) * TKB;                                              \
        _Pragma("unroll")                                                          \
        for (int i = 0; i < 2; ++i) {                                              \
            const int c    = i * 256 + tid;                                        \
            const int rowc = c >> 2;                                               \
            const int kcs  = (c & 3) ^ (rowc & 3);                                 \
            const unsigned char* gA = A4 + (size_t)(rbase + rowc) * RPB + kbase + kcs * 16; \
            const unsigned char* gB = A4 + (size_t)(cbase + rowc) * RPB + kbase + kcs * 16; \
            const int ldsOff = i * 4096 + wid * 1024;   /* +lane*16 by HW */       \
            __builtin_amdgcn_global_load_lds(                                      \
                (const __attribute__((address_space(1))) void*)gA,                 \
                (__attribute__((address_space(3))) void*)(As + ldsOff),            \
                16, 0, 0);                                                         \
            __builtin_amdgcn_global_load_lds(                                      \
                (const __attribute__((address_space(1))) void*)gB,                 \
                (__attribute__((address_space(3))) void*)(Bs + ldsOff),            \
                16, 0, 0);                                                         \
        }                                                                          \
    }

    const int t = lane >> 4;        // K-group 0..3 (32 k-elems = 16B each)
    const i32x4 Z4 = (i32x4){0, 0, 0, 0};

    STAGE(0);
    __syncthreads();                // tile 0 resident

    for (int kt = 0; kt < NKT; ++kt) {
        // ---- phase A: pull all fragments of tile kt into registers
        i32x8 a8[4], b8[4];
        #pragma unroll
        for (int m = 0; m < 4; ++m) {
            const int rowa = wr * 64 + m * 16 + (lane & 15);
            const int ph   = ((t ^ (rowa & 3)) << 4);
            i32x4 q = *(const i32x4*)(As + rowa * TKB + ph);
            a8[m] = __builtin_shufflevector(q, Z4, 0, 1, 2, 3, 4, 5, 6, 7);
        }
        #pragma unroll
        for (int n = 0; n < 4; ++n) {
            const int rowb = wc * 64 + n * 16 + (lane & 15);
            const int ph   = ((t ^ (rowb & 3)) << 4);
            i32x4 q = *(const i32x4*)(Bs + rowb * TKB + ph);
            b8[n] = __builtin_shufflevector(q, Z4, 0, 1, 2, 3, 4, 5, 6, 7);
        }
        __syncthreads();            // lgkm(0): all waves' LDS reads complete

        // ---- phase B: refill LDS for kt+1 while MFMAs run from registers
        if (kt + 1 < NKT) STAGE(kt + 1);

        __builtin_amdgcn_s_setprio(1);
        #pragma unroll
        for (int m = 0; m < 4; ++m)
            #pragma unroll
            for (int n = 0; n < 4; ++n)
                acc[m][n] = __builtin_amdgcn_mfma_scale_f32_16x16x128_f8f6f4(
                    a8[m], b8[n], acc[m][n],
                    4 /*A fmt fp4*/, 4 /*B fmt fp4*/,
                    0, 0x7F /*scaleA = 2^0*/, 0, 0x7F /*scaleB = 2^0*/);
        __builtin_amdgcn_s_setprio(0);

        __syncthreads();            // drains vmcnt(0): tile kt+1 resident
    }

    // ---------------- epilogue ----------------
    float sum_p[16], pos_p[16], cnt_p[16];
    #pragma unroll
    for (int i = 0; i < 16; ++i) { sum_p[i] = 0.f; pos_p[i] = 0.f; cnt_p[i] = 0.f; }
    float csum[4], cpos[4], ccnt[4];
    #pragma unroll
    for (int n = 0; n < 4; ++n) { csum[n] = 0.f; cpos[n] = 0.f; ccnt[n] = 0.f; }

    if (isDiag) {
        #pragma unroll
        for (int m = 0; m < 4; ++m)
            #pragma unroll
            for (int n = 0; n < 4; ++n) {
                const int gcol = col0 + n * 16;
                #pragma unroll
                for (int r = 0; r < 4; ++r) {
                    const float s    = acc[m][n][r] * SCL;
                    const int   i16  = m * 4 + r;
                    const int   grow = rowq + m * 16 + r;
                    const bool  diag = (grow == gcol);
                    sum_p[i16] += diag ? 0.f : __expf(s);
                    if ((labr[i16] == labc[n]) && !diag) {
                        pos_p[i16] += s; cnt_p[i16] += 1.f;
                    }
                }
            }
    } else {
        #pragma unroll
        for (int m = 0; m < 4; ++m)
            #pragma unroll
            for (int n = 0; n < 4; ++n) {
                #pragma unroll
                for (int r = 0; r < 4; ++r) {
                    const float s   = acc[m][n][r] * SCL;
                    const int   i16 = m * 4 + r;
                    const float e   = __expf(s);
                    sum_p[i16] += e;
                    csum[n]    += e;
                    if (labr[i16] == labc[n]) {
                        pos_p[i16] += s; cnt_p[i16] += 1.f;
                        cpos[n]    += s; ccnt[n]    += 1.f;
                    }
                }
            }
    }

    // row-side: reduce across 16 lanes sharing each row -> partial[ct*2+wc][row]
    #pragma unroll
    for (int i = 0; i < 16; ++i) {
        float se = sum_p[i], pp = pos_p[i], cc = cnt_p[i];
        #pragma unroll
        for (int off = 1; off < 16; off <<= 1) {
            se += __shfl_xor(se, off, 16);
            pp += __shfl_xor(pp, off, 16);
            cc += __shfl_xor(cc, off, 16);
        }
        if ((lane & 15) == 0) {
            const int row = rowq + (i >> 2) * 16 + (i & 3);
            const size_t idx = (size_t)(ct * 2 + wc) * N_ROWS + row;
            psum[idx] = se;
            ppos[idx] = pp;
            pcnt[idx] = cc;
        }
    }

    // col-side (off-diag only): reduce across 4 lane-groups -> partial[rt*2+wr][col]
    if (!isDiag) {
        #pragma unroll
        for (int n = 0; n < 4; ++n) {
            float se = csum[n], pp = cpos[n], cc = ccnt[n];
            se += __shfl_xor(se, 16, 64); se += __shfl_xor(se, 32, 64);
            pp += __shfl_xor(pp, 16, 64); pp += __shfl_xor(pp, 32, 64);
            cc += __shfl_xor(cc, 16, 64); cc += __shfl_xor(cc, 32, 64);
            if (lane < 16) {
                const int gcol = col0 + n * 16;
                const size_t idx = (size_t)(rt * 2 + wr) * N_ROWS + gcol;
                psum[idx] = se;
                ppos[idx] = pp;
                pcnt[idx] = cc;
            }
        }
    }
}

// ---------------- kernel 3: fused finalize (per-row logsumexp + global sum) ----
__global__ __launch_bounds__(256) void finalize_kernel(
    const float* __restrict__ psum, const float* __restrict__ ppos,
    const float* __restrict__ pcnt, float* __restrict__ out)
{
    const int row  = blockIdx.x * 256 + threadIdx.x;
    const int lane = threadIdx.x & 63, wid = threadIdx.x >> 6;

    float s = 0.f, p = 0.f, c = 0.f;
    #pragma unroll 8
    for (int sl = 0; sl < NSLICE; ++sl) {
        const size_t idx = (size_t)sl * N_ROWS + row;
        s += psum[idx];
        p += ppos[idx];
        c += pcnt[idx];
    }
    float per = (c > 0.f) ? (logf(s) - p / c) : 0.f;
    #pragma unroll
    for (int off = 32; off > 0; off >>= 1) per += __shfl_down(per, off, 64);
    __shared__ float w4[4];
    if (lane == 0) w4[wid] = per;
    __syncthreads();
    if (threadIdx.x == 0)
        atomicAdd(out, w4[0] + w4[1] + w4[2] + w4[3]);
}

extern "C" void kernel_launch(void* const* d_in, const int* in_sizes, int n_in,
                              void* d_out, int out_size, void* d_ws, size_t ws_size,
                              hipStream_t stream) {
    const float* V      = (const float*)d_in[0];
    const int*   labels = (const int*)d_in[1];
    float*       out    = (float*)d_out;

    // ws layout: A4 4 MB | psum 4 MB | ppos 4 MB | pcnt 4 MB
    unsigned char* A4 = (unsigned char*)d_ws;
    char* base = (char*)d_ws + (size_t)N_ROWS * RPB;
    float* psum = (float*)(base);
    float* ppos = (float*)(base + (size_t)NSLICE * N_ROWS * 4);
    float* pcnt = (float*)(base + (size_t)NSLICE * N_ROWS * 8);

    hipMemsetAsync(out, 0, sizeof(float), stream);
    norm_kernel<<<N_ROWS, 256, 0, stream>>>(V, A4);
    sim_kernel<<<NPAIR, 256, 0, stream>>>(A4, labels, psum, ppos, pcnt);
    finalize_kernel<<<N_ROWS / 256, 256, 0, stream>>>(psum, ppos, pcnt, out);
}